// Round 12
// baseline (187.735 us; speedup 1.0000x reference)
//
#include <hip/hip_runtime.h>

#define NA 150381
#define NC 90
#define CMAX 4096
#define MDET 100
#define STHR 0.996f
#define NTHR 0.5f
#define IMGF 896.0f
#define CPAD 32     // counts padded: one 128B cacheline per class
#define NBF 1056    // global score histogram bins ((bits-SB)>>6, padded)
#define KSEL 768    // global selection target (>= MDET + suppression slack)
#define KCAP 1024   // primary list capacity
#define K2CAP 2048  // fallback list capacity

typedef unsigned long long u64;

__device__ __forceinline__ int binf(unsigned bits, unsigned SB) {
  int b = (int)((bits - SB) >> 6);
  return b < NBF - 1 ? b : NBF - 1;
}
// single source of truth for box decode -> bit-identical everywhere
__device__ __forceinline__ float4 decode_box(float4 a, float4 r) {
  float cxa = (a.x + a.z) * 0.5f, cya = (a.y + a.w) * 0.5f;
  float wa = a.z - a.x, ha = a.w - a.y;
  float w = expf(r.w) * wa, h = expf(r.z) * ha;
  float cy = r.x * ha + cya, cx = r.y * wa + cxa;
  float4 b;
  b.x = fminf(fmaxf(cx - w * 0.5f, 0.f), IMGF);
  b.y = fminf(fmaxf(cy - h * 0.5f, 0.f), IMGF);
  b.z = fminf(fmaxf(cx + w * 0.5f, 0.f), IMGF);
  b.w = fminf(fmaxf(cy + h * 0.5f, 0.f), IMGF);
  return b;
}
__device__ __forceinline__ bool iou_gt(float x1, float y1, float x2, float y2, float a1,
                                       float u1, float v1, float u2, float v2, float a2) {
  float ix1 = fmaxf(x1, u1), iy1 = fmaxf(y1, v1);
  float ix2 = fminf(x2, u2), iy2 = fminf(y2, v2);
  float iw = fmaxf(ix2 - ix1, 0.f), ih = fmaxf(iy2 - iy1, 0.f);
  float inter = iw * ih;
  float uni = a1 + a2 - inter;
  return inter / fmaxf(uni, 1e-9f) > NTHR;
}

// ---------------- zero counters + global hist + select counter ----------------
__global__ void k_zero(int* __restrict__ counts, int* __restrict__ ghist,
                       int* __restrict__ gcnt) {
  int i = blockIdx.x * blockDim.x + threadIdx.x;
  if (i < NC * CPAD) counts[i] = 0;
  else if (i < NC * CPAD + NBF) ghist[i - NC * CPAD] = 0;
  else if (i == NC * CPAD + NBF) *gcnt = 0;
}

// ---------------- threshold filter -> per-class lists + global histogram ------
// key = score_bits<<32 | (0xFFFFFFFF - (c<<18 | anchor)): u64-desc order ==
// (score desc, class asc, anchor asc) == reference flat-index tie order.
__global__ void k_collect(const float4* __restrict__ cls4, int* __restrict__ counts,
                          u64* __restrict__ cand, int* __restrict__ ghist) {
  const unsigned SB = __float_as_uint(STHR);
  const int total = NA * NC;
  const int nv4 = total >> 2;
  const int stride = gridDim.x * blockDim.x;
  for (int q = blockIdx.x * blockDim.x + threadIdx.x; q < nv4; q += stride) {
    float4 v4 = cls4[q];
    float vv[4] = {v4.x, v4.y, v4.z, v4.w};
    #pragma unroll
    for (int e = 0; e < 4; ++e) {
      float v = vv[e];
      if (v > STHR) {
        int f = q * 4 + e;
        int c = f % NC;
        int i = f / NC;
        unsigned bits = __float_as_uint(v);
        int pos = atomicAdd(&counts[c * CPAD], 1);
        if (pos < CMAX)
          cand[(size_t)c * CMAX + pos] =
              ((u64)bits << 32) |
              (u64)(0xFFFFFFFFu - (((unsigned)c << 18) | (unsigned)i));
        atomicAdd(&ghist[binf(bits, SB)], 1);
      }
    }
  }
  int g = blockIdx.x * blockDim.x + threadIdx.x;
  if (g < total - nv4 * 4) {
    int f = nv4 * 4 + g;
    float v = ((const float*)cls4)[f];
    if (v > STHR) {
      int c = f % NC;
      int i = f / NC;
      unsigned bits = __float_as_uint(v);
      int pos = atomicAdd(&counts[c * CPAD], 1);
      if (pos < CMAX)
        cand[(size_t)c * CMAX + pos] =
            ((u64)bits << 32) |
            (u64)(0xFFFFFFFFu - (((unsigned)c << 18) | (unsigned)i));
      atomicAdd(&ghist[binf(bits, SB)], 1);
    }
  }
}

// ---------------- global radix-select: compact top-~KSEL keys into gsel ----------
__global__ __launch_bounds__(256) void k_select(const int* __restrict__ counts,
                                                const u64* __restrict__ cand,
                                                const int* __restrict__ ghist,
                                                int* __restrict__ gcnt,
                                                u64* __restrict__ gsel) {
  __shared__ int s_B;
  __shared__ int wsum[4], wsuf[4];
  const int tid = threadIdx.x, lane = tid & 63, wv = tid >> 6;
  const int c = blockIdx.x;
  const unsigned SB = __float_as_uint(STHR);

  // threshold bin B: smallest bin with suffix >= KSEL (identical in all blocks)
  const int CH = (NBF + 255) >> 8;           // 5 bins/thread
  int clo = tid * CH, chi = min(clo + CH, NBF);
  int s = 0;
  for (int b = clo; b < chi; ++b) s += ghist[b];
  int ss = s;
  for (int d = 1; d < 64; d <<= 1) {
    int v = __shfl_down(ss, d);
    if (lane + d < 64) ss += v;
  }
  if (lane == 0) wsum[wv] = ss;
  if (tid == 0) s_B = 0;                     // default: take all (total < KSEL)
  __syncthreads();
  if (tid < 4) {
    int x = wsum[tid];
    for (int d = 1; d < 4; d <<= 1) {
      int v = __shfl_down(x, d);
      if (tid + d < 4) x += v;
    }
    wsuf[tid] = x;
  }
  __syncthreads();
  int suff = ss + ((wv < 3) ? wsuf[wv + 1] : 0);
  int suffn = suff - s;
  if (suff >= KSEL && suffn < KSEL) {
    int after = suffn, B = clo;
    for (int b = chi - 1; b >= clo; --b) {
      after += ghist[b];
      if (after >= KSEL) { B = b; break; }
    }
    s_B = B;
  }
  __syncthreads();
  const int B = s_B;

  const int M = min(counts[c * CPAD], CMAX);
  for (int t = tid; t < M; t += 256) {
    u64 k = cand[(size_t)c * CMAX + t];
    if (binf((unsigned)(k >> 32), SB) >= B) {
      int p = atomicAdd(gcnt, 1);
      if (p < KCAP) gsel[p] = k;
    }
  }
}

// ---------------- one block: sort top-K, per-class NMS fixpoint, output 100 ------
__global__ __launch_bounds__(1024) void k_top(const int* __restrict__ counts,
                                              const u64* __restrict__ cand,
                                              const int* __restrict__ ghist,
                                              const int* __restrict__ gcnt,
                                              const u64* __restrict__ gsel,
                                              const float4* __restrict__ anc,
                                              const float4* __restrict__ reg,
                                              const float* __restrict__ ta,
                                              const float* __restrict__ td,
                                              const float* __restrict__ rot,
                                              float* __restrict__ out) {
  extern __shared__ u64 dyn[];
  u64* skey = dyn;                                     // [2048] 16 KB
  float* bx1 = (float*)(dyn + 2048);                   // 5 x [2048] 40 KB
  float* by1 = bx1 + 2048; float* bx2 = by1 + 2048;
  float* by2 = bx2 + 2048; float* ar  = by2 + 2048;
  unsigned short* scls = (unsigned short*)(ar + 2048); // [2048] 4 KB
  unsigned char*  alv  = (unsigned char*)(scls + 2048);// [2048] 2 KB
  __shared__ u64 sK[16];
  __shared__ int keptlist[MDET];
  __shared__ int redc[NC];
  __shared__ int wsum[16], wsuf[16];
  __shared__ int s_total, s_chg, s_ovf, s_cnt2, s_B2, s_kept;

  const int tid = threadIdx.x;
  const int wv = tid >> 6, lane = tid & 63;
  const unsigned SB = __float_as_uint(STHR);

  if (tid < NC) redc[tid] = min(counts[tid * CPAD], CMAX);
  if (tid < MDET) keptlist[tid] = -1;
  if (tid == 0) { s_ovf = 0; s_cnt2 = 0; s_kept = 0; }
  __syncthreads();
  if (tid == 0) { int t = 0; for (int i = 0; i < NC; ++i) t += redc[i]; s_total = t; }
  __syncthreads();
  const int total = s_total;
  const int gc = *gcnt;
  bool fallback = (gc > KCAP);

  if (!fallback) {
    // ---- element/thread bitonic sort of 1024 (shfl j<64, LDS j>=64) ----
    u64 v = (tid < gc) ? gsel[tid] : 0ULL;
    for (int k = 2; k <= 1024; k <<= 1) {
      for (int j = k >> 1; j > 0; j >>= 1) {
        u64 p;
        if (j >= 64) {
          __syncthreads(); skey[tid] = v; __syncthreads();
          p = skey[tid ^ j];
        } else {
          p = __shfl_xor(v, j, 64);
        }
        u64 mx = (v >= p) ? v : p, mn = (v >= p) ? p : v;
        bool takeMax = (((tid & k) == 0) != ((tid & j) != 0));
        v = takeMax ? mx : mn;
      }
    }
    __syncthreads();
    skey[tid] = v;

    // ---- decode + stage boxes/class ----
    float mx1 = 0, my1 = 0, mx2 = 0, my2 = 0, mar = 0;
    int myc = -1;
    if (tid < gc) {
      unsigned u = 0xFFFFFFFFu - (unsigned)v;
      myc = (int)(u >> 18);
      unsigned aidx = u & 0x3FFFFu;
      float4 b = decode_box(anc[aidx], reg[aidx]);
      mx1 = b.x; my1 = b.y; mx2 = b.z; my2 = b.w;
      mar = (b.z - b.x) * (b.w - b.y);
      bx1[tid] = b.x; by1[tid] = b.y; bx2[tid] = b.z; by2[tid] = b.w;
      ar[tid] = mar; scls[tid] = (unsigned short)myc;
    }
    __syncthreads();

    // ---- per-column suppressor list (same-class predecessors, IoU>thr), cap 8 ----
    u64 sup0 = 0, sup1 = 0; int cnt = 0;
    for (int s = 0; s < gc - 1; ++s) {
      if (s < tid && tid < gc && (int)scls[s] == myc) {
        if (iou_gt(mx1, my1, mx2, my2, mar, bx1[s], by1[s], bx2[s], by2[s], ar[s])) {
          if (cnt < 4) sup0 |= ((u64)(unsigned)s) << (16 * cnt);
          else if (cnt < 8) sup1 |= ((u64)(unsigned)s) << (16 * (cnt - 4));
          else s_ovf = 1;
          ++cnt;
        }
      }
    }
    __syncthreads();

    if (!s_ovf) {
      // ---- Jacobi fixpoint on kept bits (unique fixpoint == greedy keep set) ----
      if (tid < 16) {
        int lo = tid << 6;
        sK[tid] = (gc <= lo) ? 0ULL : ((gc - lo >= 64) ? ~0ULL : ((1ULL << (gc - lo)) - 1));
      }
      __syncthreads();
      for (int it = 0; it < 1024; ++it) {
        if (tid == 0) s_chg = 0;
        __syncthreads();
        bool alive = (tid < gc);
        if (alive && cnt > 0) {
          int n = min(cnt, 8);
          for (int q = 0; q < n; ++q) {
            int s = (int)((q < 4 ? (sup0 >> (16 * q)) : (sup1 >> (16 * (q - 4)))) & 0xFFFFULL);
            if ((sK[s >> 6] >> (s & 63)) & 1ULL) { alive = false; break; }
          }
        }
        u64 nw = __ballot(alive);
        __syncthreads();                    // all sK reads complete before writes
        if (lane == 0 && nw != sK[wv]) { sK[wv] = nw; s_chg = 1; }
        __syncthreads();
        if (!s_chg) break;
      }
      if (tid == 0) {
        int kt = 0;
        for (int w = 0; w < 16; ++w) kt += __popcll(sK[w]);
        s_kept = kt;
      }
      __syncthreads();
      if (s_kept >= MDET || gc >= total) {
        if (tid < gc && ((sK[wv] >> lane) & 1ULL)) {
          int slot = __popcll(sK[wv] & ((1ULL << lane) - 1ULL));
          for (int w = 0; w < wv; ++w) slot += __popcll(sK[w]);
          if (slot < MDET) keptlist[slot] = tid;
        }
      } else {
        fallback = true;                    // need deeper list (never on this data)
      }
    } else {
      fallback = true;                      // suppressor-list overflow
    }
    __syncthreads();
  }

  if (fallback) {
    // ---- exact fallback: bin-complete prefix <= K2CAP, LDS sort, serial greedy ----
    {
      int b0 = 2 * tid;
      int h0 = (b0 < NBF) ? ghist[b0] : 0;
      int h1 = (b0 + 1 < NBF) ? ghist[b0 + 1] : 0;
      int s = h0 + h1;
      int ss = s;
      for (int d = 1; d < 64; d <<= 1) {
        int v = __shfl_down(ss, d);
        if (lane + d < 64) ss += v;
      }
      if (lane == 0) wsum[wv] = ss;
      if (tid == 0) s_B2 = 0;
      __syncthreads();
      if (tid < 16) {
        int x = wsum[tid];
        for (int d = 1; d < 16; d <<= 1) {
          int v = __shfl_down(x, d);
          if (tid + d < 16) x += v;
        }
        wsuf[tid] = x;
      }
      __syncthreads();
      int suff = ss + ((wv < 15) ? wsuf[wv + 1] : 0);
      int suffn = suff - s;
      if (suff >= K2CAP && suffn < K2CAP) {
        int Bx = (suffn + h1 >= K2CAP) ? (b0 + 1) : b0;
        s_B2 = Bx + 1;                      // strictly-above prefix, count < K2CAP
      }
      __syncthreads();
    }
    const int B2 = s_B2;
    for (int c = 0; c < NC; ++c) {
      int M = redc[c];
      for (int t = tid; t < M; t += 1024) {
        u64 k = cand[(size_t)c * CMAX + t];
        if (binf((unsigned)(k >> 32), SB) >= B2) {
          int p = atomicAdd(&s_cnt2, 1);
          if (p < K2CAP) skey[p] = k;
        }
      }
    }
    __syncthreads();
    const int gc2 = min(s_cnt2, K2CAP);
    int NS2 = 2;
    while (NS2 < gc2) NS2 <<= 1;
    for (int t = tid; t < NS2; t += 1024) if (t >= gc2) skey[t] = 0ULL;
    for (int k = 2; k <= NS2; k <<= 1) {
      for (int j = k >> 1; j > 0; j >>= 1) {
        __syncthreads();
        for (int i = tid; i < NS2; i += 1024) {
          int ixj = i ^ j;
          if (ixj > i) {
            u64 x = skey[i], y = skey[ixj];
            if (((i & k) == 0) ? (x < y) : (x > y)) { skey[i] = y; skey[ixj] = x; }
          }
        }
      }
    }
    __syncthreads();
    for (int t = tid; t < gc2; t += 1024) {
      u64 k = skey[t];
      unsigned u = 0xFFFFFFFFu - (unsigned)k;
      unsigned aidx = u & 0x3FFFFu;
      float4 b = decode_box(anc[aidx], reg[aidx]);
      bx1[t] = b.x; by1[t] = b.y; bx2[t] = b.z; by2[t] = b.w;
      ar[t] = (b.z - b.x) * (b.w - b.y);
      scls[t] = (unsigned short)(u >> 18);
      alv[t] = 1;
    }
    __syncthreads();
    if (tid < 64) {                          // exact wave-serial greedy, cap MDET
      int kept = 0;
      for (int i = 0; i < gc2 && kept < MDET; ++i) {
        if (!alv[i]) continue;
        if (tid == 0) keptlist[kept] = i;
        float x1 = bx1[i], y1 = by1[i], x2 = bx2[i], y2 = by2[i], ai = ar[i];
        unsigned short ci = scls[i];
        for (int j = i + 1 + tid; j < gc2; j += 64)
          if (alv[j] && scls[j] == ci &&
              iou_gt(x1, y1, x2, y2, ai, bx1[j], by1[j], bx2[j], by2[j], ar[j]))
            alv[j] = 0;
        ++kept;
      }
    }
    __syncthreads();
  }

  // ---- output: first MDET kept in sorted order (== global top-100 kept) ----
  if (tid < MDET) {
    int r = keptlist[tid];
    bool ok = (r >= 0);
    float b0 = -1.f, b1 = -1.f, b2 = -1.f, b3 = -1.f;
    float r0 = -1.f, r1 = -1.f, r2 = -1.f;
    float t0 = -1.f, t1 = -1.f, t2 = -1.f;
    float sc = -1.f, lab = -1.f;
    if (ok) {
      u64 key = skey[r];
      sc = __uint_as_float((unsigned)(key >> 32));
      unsigned u = 0xFFFFFFFFu - (unsigned)key;
      int c = (int)(u >> 18);
      unsigned aidx = u & 0x3FFFFu;
      float4 bb = decode_box(anc[aidx], reg[aidx]);
      b0 = bb.x; b1 = bb.y; b2 = bb.z; b3 = bb.w;
      lab = (float)c;
      r0 = rot[aidx * 3 + 0]; r1 = rot[aidx * 3 + 1]; r2 = rot[aidx * 3 + 2];
      float st = ta[aidx * 3 + 2];
      t0 = ta[aidx * 3 + 0] + td[aidx * 3 + 0] * st;
      t1 = ta[aidx * 3 + 1] + td[aidx * 3 + 1] * st;
      t2 = td[aidx * 3 + 2];
    }
    out[tid * 4 + 0] = b0; out[tid * 4 + 1] = b1;
    out[tid * 4 + 2] = b2; out[tid * 4 + 3] = b3;
    out[400 + tid] = sc;
    out[500 + tid] = lab;
    out[600 + tid * 3 + 0] = r0; out[600 + tid * 3 + 1] = r1; out[600 + tid * 3 + 2] = r2;
    out[900 + tid * 3 + 0] = t0; out[900 + tid * 3 + 1] = t1; out[900 + tid * 3 + 2] = t2;
  }
}

extern "C" void kernel_launch(void* const* d_in, const int* in_sizes, int n_in,
                              void* d_out, int out_size, void* d_ws, size_t ws_size,
                              hipStream_t stream) {
  const float* anchors        = (const float*)d_in[0];
  const float* regression     = (const float*)d_in[1];
  const float* classification = (const float*)d_in[2];
  const float* rotation       = (const float*)d_in[3];
  const float* tanch          = (const float*)d_in[4];
  const float* tdelta         = (const float*)d_in[5];
  float* out = (float*)d_out;

  char* ws = (char*)d_ws;
  size_t off = 0;
  auto alloc = [&](size_t bytes) -> void* {
    void* p = ws + off;
    off += (bytes + 255) & ~(size_t)255;
    return p;
  };
  int* counts = (int*)alloc(NC * CPAD * 4);
  int* ghist  = (int*)alloc(NBF * 4);
  int* gcnt   = (int*)alloc(4);
  u64* cand   = (u64*)alloc((size_t)NC * CMAX * 8);
  u64* gsel   = (u64*)alloc((size_t)KCAP * 8);

  k_zero<<<(NC * CPAD + NBF + 1 + 255) / 256, 256, 0, stream>>>(counts, ghist, gcnt);
  k_collect<<<2048, 256, 0, stream>>>((const float4*)classification, counts, cand, ghist);
  k_select<<<NC, 256, 0, stream>>>(counts, cand, ghist, gcnt, gsel);

  hipFuncSetAttribute(reinterpret_cast<const void*>(k_top),
                      hipFuncAttributeMaxDynamicSharedMemorySize, 65536);
  k_top<<<1, 1024, 65536, stream>>>(counts, cand, ghist, gcnt, gsel,
                                    (const float4*)anchors, (const float4*)regression,
                                    tanch, tdelta, rotation, out);
}

// Round 13
// 54.550 us; speedup vs baseline: 3.4415x; 3.4415x over previous
//
#include <hip/hip_runtime.h>

#define NA 150381
#define NC 90
#define CMAX 4096
#define MDET 100
#define STHR 0.996f
#define NTHR 0.5f
#define IMGF 896.0f
#define CPAD 32     // counts padded: one 128B cacheline per class
#define NBF 1056    // global score histogram bins ((bits-SB)>>6, padded)
#define KSEL 384    // global selection target (>= MDET + suppression slack)
#define KCAP 512    // primary list capacity (8 x u64 kept-words)
#define NW 8        // KCAP/64
#define K2CAP 2048  // fallback list capacity

typedef unsigned long long u64;

__device__ __forceinline__ int binf(unsigned bits, unsigned SB) {
  int b = (int)((bits - SB) >> 6);
  return b < NBF - 1 ? b : NBF - 1;
}
// single source of truth for box decode -> bit-identical everywhere
__device__ __forceinline__ float4 decode_box(float4 a, float4 r) {
  float cxa = (a.x + a.z) * 0.5f, cya = (a.y + a.w) * 0.5f;
  float wa = a.z - a.x, ha = a.w - a.y;
  float w = expf(r.w) * wa, h = expf(r.z) * ha;
  float cy = r.x * ha + cya, cx = r.y * wa + cxa;
  float4 b;
  b.x = fminf(fmaxf(cx - w * 0.5f, 0.f), IMGF);
  b.y = fminf(fmaxf(cy - h * 0.5f, 0.f), IMGF);
  b.z = fminf(fmaxf(cx + w * 0.5f, 0.f), IMGF);
  b.w = fminf(fmaxf(cy + h * 0.5f, 0.f), IMGF);
  return b;
}
__device__ __forceinline__ bool iou_gt(float x1, float y1, float x2, float y2, float a1,
                                       float u1, float v1, float u2, float v2, float a2) {
  float ix1 = fmaxf(x1, u1), iy1 = fmaxf(y1, v1);
  float ix2 = fminf(x2, u2), iy2 = fminf(y2, v2);
  float iw = fmaxf(ix2 - ix1, 0.f), ih = fmaxf(iy2 - iy1, 0.f);
  float inter = iw * ih;
  float uni = a1 + a2 - inter;
  return inter / fmaxf(uni, 1e-9f) > NTHR;
}

// ---------------- zero counters + global hist + select counter ----------------
__global__ void k_zero(int* __restrict__ counts, int* __restrict__ ghist,
                       int* __restrict__ gcnt) {
  int i = blockIdx.x * blockDim.x + threadIdx.x;
  if (i < NC * CPAD) counts[i] = 0;
  else if (i < NC * CPAD + NBF) ghist[i - NC * CPAD] = 0;
  else if (i == NC * CPAD + NBF) *gcnt = 0;
}

// ---------------- threshold filter -> per-class lists + global histogram ------
// key = score_bits<<32 | (0xFFFFFFFF - (c<<18 | anchor)): u64-desc order ==
// (score desc, class asc, anchor asc) == reference flat-index tie order.
__global__ void k_collect(const float4* __restrict__ cls4, int* __restrict__ counts,
                          u64* __restrict__ cand, int* __restrict__ ghist) {
  const unsigned SB = __float_as_uint(STHR);
  const int total = NA * NC;
  const int nv4 = total >> 2;
  const int stride = gridDim.x * blockDim.x;
  for (int q = blockIdx.x * blockDim.x + threadIdx.x; q < nv4; q += stride) {
    float4 v4 = cls4[q];
    float vv[4] = {v4.x, v4.y, v4.z, v4.w};
    #pragma unroll
    for (int e = 0; e < 4; ++e) {
      float v = vv[e];
      if (v > STHR) {
        int f = q * 4 + e;
        int c = f % NC;
        int i = f / NC;
        unsigned bits = __float_as_uint(v);
        int pos = atomicAdd(&counts[c * CPAD], 1);
        if (pos < CMAX)
          cand[(size_t)c * CMAX + pos] =
              ((u64)bits << 32) |
              (u64)(0xFFFFFFFFu - (((unsigned)c << 18) | (unsigned)i));
        atomicAdd(&ghist[binf(bits, SB)], 1);
      }
    }
  }
  int g = blockIdx.x * blockDim.x + threadIdx.x;
  if (g < total - nv4 * 4) {
    int f = nv4 * 4 + g;
    float v = ((const float*)cls4)[f];
    if (v > STHR) {
      int c = f % NC;
      int i = f / NC;
      unsigned bits = __float_as_uint(v);
      int pos = atomicAdd(&counts[c * CPAD], 1);
      if (pos < CMAX)
        cand[(size_t)c * CMAX + pos] =
            ((u64)bits << 32) |
            (u64)(0xFFFFFFFFu - (((unsigned)c << 18) | (unsigned)i));
      atomicAdd(&ghist[binf(bits, SB)], 1);
    }
  }
}

// ---------------- global radix-select: compact top-~KSEL keys into gsel ----------
__global__ __launch_bounds__(256) void k_select(const int* __restrict__ counts,
                                                const u64* __restrict__ cand,
                                                const int* __restrict__ ghist,
                                                int* __restrict__ gcnt,
                                                u64* __restrict__ gsel) {
  __shared__ int s_B;
  __shared__ int wsum[4], wsuf[4];
  const int tid = threadIdx.x, lane = tid & 63, wv = tid >> 6;
  const int c = blockIdx.x;
  const unsigned SB = __float_as_uint(STHR);

  // threshold bin B: smallest bin with suffix >= KSEL (identical in all blocks)
  const int CH = (NBF + 255) >> 8;           // 5 bins/thread
  int clo = tid * CH, chi = min(clo + CH, NBF);
  int s = 0;
  for (int b = clo; b < chi; ++b) s += ghist[b];
  int ss = s;
  for (int d = 1; d < 64; d <<= 1) {
    int v = __shfl_down(ss, d);
    if (lane + d < 64) ss += v;
  }
  if (lane == 0) wsum[wv] = ss;
  if (tid == 0) s_B = 0;                     // default: take all (total < KSEL)
  __syncthreads();
  if (tid < 4) {
    int x = wsum[tid];
    for (int d = 1; d < 4; d <<= 1) {
      int v = __shfl_down(x, d);
      if (tid + d < 4) x += v;
    }
    wsuf[tid] = x;
  }
  __syncthreads();
  int suff = ss + ((wv < 3) ? wsuf[wv + 1] : 0);
  int suffn = suff - s;
  if (suff >= KSEL && suffn < KSEL) {
    int after = suffn, B = clo;
    for (int b = chi - 1; b >= clo; --b) {
      after += ghist[b];
      if (after >= KSEL) { B = b; break; }
    }
    s_B = B;
  }
  __syncthreads();
  const int B = s_B;

  const int M = min(counts[c * CPAD], CMAX);
  for (int t = tid; t < M; t += 256) {
    u64 k = cand[(size_t)c * CMAX + t];
    if (binf((unsigned)(k >> 32), SB) >= B) {
      int p = atomicAdd(gcnt, 1);
      if (p < KCAP) gsel[p] = k;
    }
  }
}

// ---------------- one block: sort top-K, class-bitmap NMS fixpoint, output 100 ----
__global__ __launch_bounds__(512) void k_top(const int* __restrict__ counts,
                                             const u64* __restrict__ cand,
                                             const int* __restrict__ ghist,
                                             const int* __restrict__ gcnt,
                                             const u64* __restrict__ gsel,
                                             const float4* __restrict__ anc,
                                             const float4* __restrict__ reg,
                                             const float* __restrict__ ta,
                                             const float* __restrict__ td,
                                             const float* __restrict__ rot,
                                             float* __restrict__ out) {
  extern __shared__ u64 dyn[];
  u64* skey = dyn;                                     // [2048] 16 KB
  float* bx1 = (float*)(dyn + 2048);                   // 5 x [2048] 40 KB
  float* by1 = bx1 + 2048; float* bx2 = by1 + 2048;
  float* by2 = bx2 + 2048; float* ar  = by2 + 2048;
  unsigned short* scls = (unsigned short*)(ar + 2048); // [2048] 4 KB
  unsigned char*  alv  = (unsigned char*)(scls + 2048);// [2048] 2 KB
  u64* classbit = (u64*)(alv + 2048);                  // [NC][NW] 5.8 KB
  __shared__ u64 sK[NW];
  __shared__ int keptlist[MDET];
  __shared__ int redc[NC];
  __shared__ int cls_seen[NC];
  __shared__ int wsum[8], wsuf[8];
  __shared__ int s_total, s_chg, s_cnt2, s_B2, s_kept;

  const int tid = threadIdx.x;
  const int wv = tid >> 6, lane = tid & 63;
  const unsigned SB = __float_as_uint(STHR);

  if (tid < NC) { redc[tid] = min(counts[tid * CPAD], CMAX); cls_seen[tid] = 0; }
  if (tid < MDET) keptlist[tid] = -1;
  if (tid == 0) { s_cnt2 = 0; s_kept = 0; }
  for (int t = tid; t < NC * NW; t += 512) classbit[t] = 0ULL;
  __syncthreads();
  if (tid == 0) { int t = 0; for (int i = 0; i < NC; ++i) t += redc[i]; s_total = t; }
  __syncthreads();
  const int total = s_total;
  const int gc = *gcnt;
  bool fallback = (gc > KCAP);

  if (!fallback) {
    // ---- element/thread bitonic sort of 512 (shfl j<64, LDS j>=64) ----
    u64 v = (tid < gc) ? gsel[tid] : 0ULL;
    for (int k = 2; k <= 512; k <<= 1) {
      for (int j = k >> 1; j > 0; j >>= 1) {
        u64 p;
        if (j >= 64) {
          __syncthreads(); skey[tid] = v; __syncthreads();
          p = skey[tid ^ j];
        } else {
          p = __shfl_xor(v, j, 64);
        }
        u64 mx = (v >= p) ? v : p, mn = (v >= p) ? p : v;
        bool takeMax = (((tid & k) == 0) != ((tid & j) != 0));
        v = takeMax ? mx : mn;
      }
    }
    __syncthreads();
    skey[tid] = v;

    // ---- decode + stage boxes/class + class bitmap ----
    float mx1 = 0, my1 = 0, mx2 = 0, my2 = 0, mar = 0;
    int myc = -1;
    if (tid < gc) {
      unsigned u = 0xFFFFFFFFu - (unsigned)v;
      myc = (int)(u >> 18);
      unsigned aidx = u & 0x3FFFFu;
      float4 b = decode_box(anc[aidx], reg[aidx]);
      mx1 = b.x; my1 = b.y; mx2 = b.z; my2 = b.w;
      mar = (b.z - b.x) * (b.w - b.y);
      bx1[tid] = b.x; by1[tid] = b.y; bx2[tid] = b.z; by2[tid] = b.w;
      ar[tid] = mar; scls[tid] = (unsigned short)myc;
      atomicOr(&classbit[myc * NW + (tid >> 6)], 1ULL << (tid & 63));
    }
    __syncthreads();

    // ---- per-thread suppressor bitmask: same-class predecessors with IoU>thr ----
    u64 sup[NW];
    #pragma unroll
    for (int w = 0; w < NW; ++w) sup[w] = 0ULL;
    if (tid < gc) {
      const int tw = tid >> 6;
      for (int w = 0; w <= tw; ++w) {
        u64 m = classbit[myc * NW + w];
        if (w == tw) m &= (tid & 63) ? ((1ULL << (tid & 63)) - 1ULL) : 0ULL;
        u64 acc = 0ULL;
        while (m) {
          int b = __ffsll(m) - 1;
          m &= m - 1ULL;
          int s = (w << 6) + b;
          if (iou_gt(mx1, my1, mx2, my2, mar, bx1[s], by1[s], bx2[s], by2[s], ar[s]))
            acc |= 1ULL << b;
        }
        sup[w] = acc;
      }
    }

    // ---- Jacobi fixpoint on kept bits (unique fixpoint == greedy keep set) ----
    if (tid < NW) {
      int lo = tid << 6;
      sK[tid] = (gc <= lo) ? 0ULL : ((gc - lo >= 64) ? ~0ULL : ((1ULL << (gc - lo)) - 1));
    }
    __syncthreads();
    for (int it = 0; it < KCAP; ++it) {
      if (tid == 0) s_chg = 0;
      __syncthreads();
      bool alive = (tid < gc);
      if (alive) {
        u64 r = 0ULL;
        #pragma unroll
        for (int w = 0; w < NW; ++w) r |= sup[w] & sK[w];
        alive = (r == 0ULL);
      }
      u64 nw = __ballot(alive);
      __syncthreads();                       // all sK reads complete before writes
      if (lane == 0 && nw != sK[wv]) { sK[wv] = nw; s_chg = 1; }
      __syncthreads();
      if (!s_chg) break;
    }
    if (tid == 0) {
      int kt = 0;
      for (int w = 0; w < NW; ++w) kt += __popcll(sK[w]);
      s_kept = kt;
    }
    __syncthreads();
    if (s_kept >= MDET || gc >= total) {
      if (tid < gc && ((sK[wv] >> lane) & 1ULL)) {
        int slot = __popcll(sK[wv] & ((1ULL << lane) - 1ULL));
        for (int w = 0; w < wv; ++w) slot += __popcll(sK[w]);
        if (slot < MDET) keptlist[slot] = tid;
      }
    } else {
      fallback = true;                       // need deeper list (never on this data)
    }
    __syncthreads();
  }

  if (fallback) {
    // ---- exact fallback: bin-complete prefix <= K2CAP, LDS sort, serial greedy ----
    {
      int b0 = 2 * tid;
      int h0 = (b0 < NBF) ? ghist[b0] : 0;
      int h1 = (b0 + 1 < NBF) ? ghist[b0 + 1] : 0;
      int s = h0 + h1;
      int ss = s;
      for (int d = 1; d < 64; d <<= 1) {
        int v = __shfl_down(ss, d);
        if (lane + d < 64) ss += v;
      }
      if (lane == 0) wsum[wv] = ss;
      if (tid == 0) s_B2 = 0;
      __syncthreads();
      if (tid < 8) {
        int x = wsum[tid];
        for (int d = 1; d < 8; d <<= 1) {
          int v = __shfl_down(x, d);
          if (tid + d < 8) x += v;
        }
        wsuf[tid] = x;
      }
      __syncthreads();
      int suff = ss + ((wv < 7) ? wsuf[wv + 1] : 0);
      int suffn = suff - s;
      if (suff >= K2CAP && suffn < K2CAP) {
        int Bx = (suffn + h1 >= K2CAP) ? (b0 + 1) : b0;
        s_B2 = Bx + 1;                       // strictly-above prefix, count < K2CAP
      }
      __syncthreads();
    }
    const int B2 = s_B2;
    for (int c = 0; c < NC; ++c) {
      int M = redc[c];
      for (int t = tid; t < M; t += 512) {
        u64 k = cand[(size_t)c * CMAX + t];
        if (binf((unsigned)(k >> 32), SB) >= B2) {
          int p = atomicAdd(&s_cnt2, 1);
          if (p < K2CAP) skey[p] = k;
        }
      }
    }
    __syncthreads();
    const int gc2 = min(s_cnt2, K2CAP);
    int NS2 = 2;
    while (NS2 < gc2) NS2 <<= 1;
    for (int t = tid; t < NS2; t += 512) if (t >= gc2) skey[t] = 0ULL;
    for (int k = 2; k <= NS2; k <<= 1) {
      for (int j = k >> 1; j > 0; j >>= 1) {
        __syncthreads();
        for (int i = tid; i < NS2; i += 512) {
          int ixj = i ^ j;
          if (ixj > i) {
            u64 x = skey[i], y = skey[ixj];
            if (((i & k) == 0) ? (x < y) : (x > y)) { skey[i] = y; skey[ixj] = x; }
          }
        }
      }
    }
    __syncthreads();
    for (int t = tid; t < gc2; t += 512) {
      u64 k = skey[t];
      unsigned u = 0xFFFFFFFFu - (unsigned)k;
      unsigned aidx = u & 0x3FFFFu;
      float4 b = decode_box(anc[aidx], reg[aidx]);
      bx1[t] = b.x; by1[t] = b.y; bx2[t] = b.z; by2[t] = b.w;
      ar[t] = (b.z - b.x) * (b.w - b.y);
      scls[t] = (unsigned short)(u >> 18);
      alv[t] = 1;
    }
    __syncthreads();
    if (tid < 64) {                          // exact wave-serial greedy, cap MDET
      int kept = 0;
      for (int i = 0; i < gc2 && kept < MDET; ++i) {
        int ci = (int)scls[i];
        int skip = 0;
        if (tid == 0) {                      // per-class PRE_K rank guard
          skip = (cls_seen[ci] >= 1024) ? 1 : 0;
          cls_seen[ci]++;
        }
        skip = __shfl(skip, 0);
        if (skip || !alv[i]) continue;
        if (tid == 0) keptlist[kept] = i;
        float x1 = bx1[i], y1 = by1[i], x2 = bx2[i], y2 = by2[i], ai = ar[i];
        for (int j = i + 1 + tid; j < gc2; j += 64)
          if (alv[j] && (int)scls[j] == ci &&
              iou_gt(x1, y1, x2, y2, ai, bx1[j], by1[j], bx2[j], by2[j], ar[j]))
            alv[j] = 0;
        ++kept;
      }
    }
    __syncthreads();
  }

  // ---- output: first MDET kept in sorted order (== global top-100 kept) ----
  if (tid < MDET) {
    int r = keptlist[tid];
    bool ok = (r >= 0);
    float b0 = -1.f, b1 = -1.f, b2 = -1.f, b3 = -1.f;
    float r0 = -1.f, r1 = -1.f, r2 = -1.f;
    float t0 = -1.f, t1 = -1.f, t2 = -1.f;
    float sc = -1.f, lab = -1.f;
    if (ok) {
      u64 key = skey[r];
      sc = __uint_as_float((unsigned)(key >> 32));
      unsigned u = 0xFFFFFFFFu - (unsigned)key;
      int c = (int)(u >> 18);
      unsigned aidx = u & 0x3FFFFu;
      float4 bb = decode_box(anc[aidx], reg[aidx]);
      b0 = bb.x; b1 = bb.y; b2 = bb.z; b3 = bb.w;
      lab = (float)c;
      r0 = rot[aidx * 3 + 0]; r1 = rot[aidx * 3 + 1]; r2 = rot[aidx * 3 + 2];
      float st = ta[aidx * 3 + 2];
      t0 = ta[aidx * 3 + 0] + td[aidx * 3 + 0] * st;
      t1 = ta[aidx * 3 + 1] + td[aidx * 3 + 1] * st;
      t2 = td[aidx * 3 + 2];
    }
    out[tid * 4 + 0] = b0; out[tid * 4 + 1] = b1;
    out[tid * 4 + 2] = b2; out[tid * 4 + 3] = b3;
    out[400 + tid] = sc;
    out[500 + tid] = lab;
    out[600 + tid * 3 + 0] = r0; out[600 + tid * 3 + 1] = r1; out[600 + tid * 3 + 2] = r2;
    out[900 + tid * 3 + 0] = t0; out[900 + tid * 3 + 1] = t1; out[900 + tid * 3 + 2] = t2;
  }
}

extern "C" void kernel_launch(void* const* d_in, const int* in_sizes, int n_in,
                              void* d_out, int out_size, void* d_ws, size_t ws_size,
                              hipStream_t stream) {
  const float* anchors        = (const float*)d_in[0];
  const float* regression     = (const float*)d_in[1];
  const float* classification = (const float*)d_in[2];
  const float* rotation       = (const float*)d_in[3];
  const float* tanch          = (const float*)d_in[4];
  const float* tdelta         = (const float*)d_in[5];
  float* out = (float*)d_out;

  char* ws = (char*)d_ws;
  size_t off = 0;
  auto alloc = [&](size_t bytes) -> void* {
    void* p = ws + off;
    off += (bytes + 255) & ~(size_t)255;
    return p;
  };
  int* counts = (int*)alloc(NC * CPAD * 4);
  int* ghist  = (int*)alloc(NBF * 4);
  int* gcnt   = (int*)alloc(4);
  u64* cand   = (u64*)alloc((size_t)NC * CMAX * 8);
  u64* gsel   = (u64*)alloc((size_t)KCAP * 8);

  k_zero<<<(NC * CPAD + NBF + 1 + 255) / 256, 256, 0, stream>>>(counts, ghist, gcnt);
  k_collect<<<2048, 256, 0, stream>>>((const float4*)classification, counts, cand, ghist);
  k_select<<<NC, 256, 0, stream>>>(counts, cand, ghist, gcnt, gsel);

  // dyn: skey 16K + boxes 40K + scls 4K + alv 2K + classbit 5.76K = ~68 KB
  hipFuncSetAttribute(reinterpret_cast<const void*>(k_top),
                      hipFuncAttributeMaxDynamicSharedMemorySize, 70912);
  k_top<<<1, 512, 70912, stream>>>(counts, cand, ghist, gcnt, gsel,
                                   (const float4*)anchors, (const float4*)regression,
                                   tanch, tdelta, rotation, out);
}